// Round 11
// baseline (205.932 us; speedup 1.0000x reference)
//
#include <hip/hip_runtime.h>
#include <cstdint>
#include <cstddef>

// ---------------------------------------------------------------------------
// GCN 3-conv + MLP head. FP16 single-product MFMA GEMMs (f32 accumulate),
// f16 activations, aggregate-before-linear (A(xW) == (Ax)W, Fin<Fout).
// 256x256 8-wave GEMM; fc2 GEMM fuses bias + log_softmax.
// Degree histogram: 4-way PLANAR-replicated packed u64 atomics
// (packed4[r*n+node] -> replicas on 4 distinct L2 lines, 4x less same-address
// AND same-line contention). CSR slots from atomic returns; atomic-free fill.
// ---------------------------------------------------------------------------

typedef _Float16 f16;
typedef _Float16 half8 __attribute__((ext_vector_type(8)));
typedef _Float16 half4 __attribute__((ext_vector_type(4)));
typedef float v4f __attribute__((ext_vector_type(4)));
typedef unsigned long long u64;

__device__ inline void gload_lds16(const void* g, void* l) {
    __builtin_amdgcn_global_load_lds(
        (const __attribute__((address_space(1))) unsigned int*)g,
        (__attribute__((address_space(3))) unsigned int*)l, 16, 0, 0);
}

// ------------------------------ graph prep --------------------------------

// one packed atomic per edge into replica plane r=(e>>2)&3; old value -> slot
__global__ __launch_bounds__(256) void k_edge1(const int* __restrict__ dst, const float* __restrict__ ew,
                                               u64* __restrict__ packed4, int* __restrict__ eslot,
                                               int E, int n) {
    int t = blockIdx.x * blockDim.x + threadIdx.x;
    int e0 = t * 4;
    int r = t & 3;
    u64* plane = packed4 + (size_t)r * n;
    if (e0 + 3 < E) {
        int4 d4 = *(const int4*)(dst + e0);
        float4 w4 = *(const float4*)(ew + e0);
        u64 a0 = ((u64)__float2uint_rn(w4.x * 1048576.f) << 24) | 1ULL;
        u64 a1 = ((u64)__float2uint_rn(w4.y * 1048576.f) << 24) | 1ULL;
        u64 a2 = ((u64)__float2uint_rn(w4.z * 1048576.f) << 24) | 1ULL;
        u64 a3 = ((u64)__float2uint_rn(w4.w * 1048576.f) << 24) | 1ULL;
        u64 o0 = atomicAdd(&plane[d4.x], a0);
        u64 o1 = atomicAdd(&plane[d4.y], a1);
        u64 o2 = atomicAdd(&plane[d4.z], a2);
        u64 o3 = atomicAdd(&plane[d4.w], a3);
        int4 s;
        s.x = (int)(o0 & 0xFFFFFF); s.y = (int)(o1 & 0xFFFFFF);
        s.z = (int)(o2 & 0xFFFFFF); s.w = (int)(o3 & 0xFFFFFF);
        *(int4*)(eslot + e0) = s;
    } else {
        for (int e = e0; e < E; ++e) {
            u64 a = ((u64)__float2uint_rn(ew[e] * 1048576.f) << 24) | 1ULL;
            u64 o = atomicAdd(&plane[dst[e]], a);
            eslot[e] = (int)(o & 0xFFFFFF);
        }
    }
}

// fused: unpack 4 planes -> dinv + per-replica bases + per-block cnt sums
__global__ __launch_bounds__(256) void k_dinv_scan1(const u64* __restrict__ packed4,
                                                    float* __restrict__ dinv, int* __restrict__ cnt,
                                                    int4* __restrict__ rbase, int* __restrict__ bsum, int n) {
    int i = blockIdx.x * 256 + threadIdx.x;
    int c = 0;
    if (i < n) {
        u64 p0 = packed4[i];
        u64 p1 = packed4[(size_t)n + i];
        u64 p2 = packed4[(size_t)2 * n + i];
        u64 p3 = packed4[(size_t)3 * n + i];
        int c0 = (int)(p0 & 0xFFFFFF), c1 = (int)(p1 & 0xFFFFFF);
        int c2 = (int)(p2 & 0xFFFFFF), c3 = (int)(p3 & 0xFFFFFF);
        c = c0 + c1 + c2 + c3;
        rbase[i] = make_int4(0, c0, c0 + c1, c0 + c1 + c2);
        float d = 1.0f + (float)((p0 >> 24) + (p1 >> 24) + (p2 >> 24) + (p3 >> 24)) * (1.0f / 1048576.f);
        float r = rsqrtf(d);
        r = r * (1.5f - 0.5f * d * r * r);
        dinv[i] = r;
        cnt[i] = c;
    }
    int v = c;
#pragma unroll
    for (int o = 32; o; o >>= 1) v += __shfl_xor(v, o);
    __shared__ int s[4];
    if ((threadIdx.x & 63) == 0) s[threadIdx.x >> 6] = v;
    __syncthreads();
    if (threadIdx.x == 0) bsum[blockIdx.x] = s[0] + s[1] + s[2] + s[3];
}

// 256-thread inclusive block scan (shfl wave scan + LDS wave offsets).
__device__ inline int block_scan_incl(int v) {
    __shared__ int ws[4];
    int lane = threadIdx.x & 63, w = threadIdx.x >> 6;
#pragma unroll
    for (int off = 1; off < 64; off <<= 1) {
        int t = __shfl_up(v, off);
        if (lane >= off) v += t;
    }
    if (lane == 63) ws[w] = v;
    __syncthreads();
    int add = 0;
#pragma unroll
    for (int i = 0; i < 4; ++i) add += (i < w) ? ws[i] : 0;
    __syncthreads();
    return v + add;
}

// fused scan2+scan3: each block sums bsum[0..blk) itself (one wave), then
// local scan + offset -> rowptr. No inter-block communication.
__global__ __launch_bounds__(256) void k_scan23(const int* __restrict__ cnt, const int* __restrict__ bsum,
                                                int* __restrict__ rowptr, int n, int E) {
    int blk = blockIdx.x, tid = threadIdx.x;
    int i = blk * 256 + tid;
    __shared__ int spre;
    if (tid < 64) {
        int s = 0;
        for (int j = tid; j < blk; j += 64) s += bsum[j];
#pragma unroll
        for (int o = 32; o; o >>= 1) s += __shfl_xor(s, o);
        if (tid == 0) spre = s;
    }
    __syncthreads();
    int v = (i < n) ? cnt[i] : 0;
    int incl = block_scan_incl(v);
    if (i < n) rowptr[i] = spre + incl - v;
    if (i == n - 1) rowptr[n] = E;
}

// atomic-free CSR fill using precomputed slots + replica bases
__global__ __launch_bounds__(256) void k_fill(const int* __restrict__ src, const int* __restrict__ dst,
                                              const float* __restrict__ ew, const int* __restrict__ eslot,
                                              const float* __restrict__ dinv, const int* __restrict__ rowptr,
                                              const int4* __restrict__ rbase,
                                              int* __restrict__ csr_src, float* __restrict__ csr_norm, int E) {
    int e = blockIdx.x * blockDim.x + threadIdx.x;
    if (e < E) {
        int d = dst[e], s = src[e];
        int r = (e >> 2) & 3;
        int4 rb = rbase[d];
        int base = (r == 0) ? rb.x : (r == 1) ? rb.y : (r == 2) ? rb.z : rb.w;
        int idx = rowptr[d] + base + eslot[e];
        csr_src[idx] = s;
        csr_norm[idx] = dinv[s] * ew[e] * dinv[d];
    }
}

// fused: packed4 init + x f32->f16 cast + 5 weight transposes W[K,N]->WT[Np,K]
struct PrepArgs {
    u64* packed4; int n4;
    const float* x; f16* xh; int xt4;
    const float* W[5]; f16* WT[5];
    int lgK[5]; int N[5]; int off[6];
};
__global__ __launch_bounds__(256) void k_prep(PrepArgs a) {
    int i = blockIdx.x * 256 + threadIdx.x;
    if (i < a.n4) { a.packed4[i] = 0ULL; return; }
    int j = i - a.n4;
    if (j < a.xt4) {
        float4 v = *(const float4*)(a.x + (size_t)j * 4);
        half4 h = {(f16)v.x, (f16)v.y, (f16)v.z, (f16)v.w};
        *(half4*)(a.xh + (size_t)j * 4) = h;
        return;
    }
    int w = j - a.xt4;
#pragma unroll
    for (int s = 0; s < 5; ++s) {
        if (w >= a.off[s] && w < a.off[s + 1]) {
            int li = w - a.off[s];
            int K = 1 << a.lgK[s];
            int nr = li >> a.lgK[s], k = li & (K - 1);
            float v = (nr < a.N[s]) ? a.W[s][(size_t)k * a.N[s] + nr] : 0.f;
            a.WT[s][li] = (f16)v;
        }
    }
}

// ------------------------------ aggregation -------------------------------
// out[i,:] = dinv[i]^2*h[i,:] + sum_j norm_j*h[src_j,:]; f16 in/out, f32 acc.
template <int F>
__global__ __launch_bounds__(256) void k_agg(const f16* __restrict__ h,
                                             const float* __restrict__ dinv, const int* __restrict__ rowptr,
                                             const int* __restrict__ csr_src, const float* __restrict__ csr_norm,
                                             f16* __restrict__ o, int n) {
    constexpr int LPN = F / 8;
    constexpr int NPW = 64 / LPN;
    int wave = (int)((blockIdx.x * (unsigned)blockDim.x + threadIdx.x) >> 6);
    int lane = threadIdx.x & 63;
    int grp = lane / LPN, lin = lane % LPN;
    int node = wave * NPW + grp;
    if (node >= n) return;
    float di = dinv[node], w0 = di * di;
    float acc[8];
#pragma unroll
    for (int i = 0; i < 8; ++i) acc[i] = 0.f;

    auto gat = [&](int s, float w) {
        half8 x = *(const half8*)(h + (size_t)s * F + lin * 8);
#pragma unroll
        for (int i = 0; i < 8; ++i) acc[i] += w * (float)x[i];
    };

    gat(node, w0);
    int beg = rowptr[node], end = rowptr[node + 1];
    int j = beg;
    for (; j + 3 < end; j += 4) {  // 4 independent gathers in flight
        int s0 = csr_src[j], s1 = csr_src[j + 1], s2 = csr_src[j + 2], s3 = csr_src[j + 3];
        float u0 = csr_norm[j], u1 = csr_norm[j + 1], u2 = csr_norm[j + 2], u3 = csr_norm[j + 3];
        gat(s0, u0); gat(s1, u1); gat(s2, u2); gat(s3, u3);
    }
    for (; j < end; ++j) gat(csr_src[j], csr_norm[j]);

    half8 v;
#pragma unroll
    for (int i = 0; i < 8; ++i) v[i] = (f16)acc[i];
    *(half8*)(o + (size_t)node * F + (size_t)lin * 8) = v;
}

// --------------------------- MFMA GEMM (small) ----------------------------
// 128x128 tile, 4 waves 2x2 (conv1 only). A,B via global_load_lds, dbuf.
template <bool RELU>
__global__ __launch_bounds__(256) void k_mm(const f16* __restrict__ A, const f16* __restrict__ BT,
                                            const float* __restrict__ bias, f16* __restrict__ Ch,
                                            int M, int N, int K, int nB, int nwg) {
    __shared__ f16 lsA[2][128 * 64];
    __shared__ f16 lsB[2][128 * 64];
    int wg = blockIdx.x;
    int q = nwg >> 3, r = nwg & 7;
    int xcd = wg & 7, lin = wg >> 3;
    int wgs = (xcd < r) ? (xcd * (q + 1) + lin) : (r * (q + 1) + (xcd - r) * q + lin);
    int bm = wgs / nB, bn = wgs % nB;

    int tid = threadIdx.x;
    int lane = tid & 63, wid = tid >> 6;
    int l16 = lane & 15, lhi = lane >> 4;
    int wm = (wid >> 1) * 64, wn = (wid & 1) * 64;
    int brow = bm * 128, bcol = bn * 128;

    v4f acc[4][4] = {};

    auto stageA = [&](int buf, int k0) {
#pragma unroll
        for (int it = 0; it < 4; ++it) {
            int b = it * 4096 + tid * 16;
            int row = b >> 7;
            int s = ((b >> 4) & 7) ^ (row & 7);
            gload_lds16(A + (size_t)(brow + row) * K + k0 + s * 8, ((char*)&lsA[buf][0]) + b);
        }
    };
    auto stageB = [&](int buf, int k0) {
#pragma unroll
        for (int it = 0; it < 4; ++it) {
            int b = it * 4096 + tid * 16;
            int row = b >> 7;
            int s = ((b >> 4) & 7) ^ (row & 7);
            gload_lds16(BT + (size_t)(bcol + row) * K + k0 + s * 8, ((char*)&lsB[buf][0]) + b);
        }
    };

    int nk = K >> 6;
    stageA(0, 0);
    stageB(0, 0);
    for (int kt = 0; kt < nk; ++kt) {
        int cur = kt & 1;
        __syncthreads();
        if (kt + 1 < nk) { stageA(cur ^ 1, (kt + 1) << 6); stageB(cur ^ 1, (kt + 1) << 6); }
#pragma unroll
        for (int ks = 0; ks < 2; ++ks) {
            half8 bf[4];
#pragma unroll
            for (int fn = 0; fn < 4; ++fn) {
                int row = wn + fn * 16 + l16;
                int sidx = (ks * 4 + lhi) ^ (row & 7);
                bf[fn] = *(const half8*)(&lsB[cur][0] + row * 64 + sidx * 8);
            }
#pragma unroll
            for (int fm = 0; fm < 4; ++fm) {
                int row = wm + fm * 16 + l16;
                int sidx = (ks * 4 + lhi) ^ (row & 7);
                half8 af = *(const half8*)(&lsA[cur][0] + row * 64 + sidx * 8);
#pragma unroll
                for (int fn = 0; fn < 4; ++fn)
                    acc[fm][fn] = __builtin_amdgcn_mfma_f32_16x16x32_f16(bf[fn], af, acc[fm][fn], 0, 0, 0);
            }
        }
    }
#pragma unroll
    for (int fm = 0; fm < 4; ++fm) {
        int m = brow + wm + fm * 16 + l16;
        if (m >= M) continue;
#pragma unroll
        for (int fn = 0; fn < 4; ++fn) {
            int nb = bcol + wn + fn * 16 + lhi * 4;
            v4f bv = *(const v4f*)(bias + nb);
            v4f v = acc[fm][fn] + bv;
            if (RELU) {
#pragma unroll
                for (int rr = 0; rr < 4; ++rr) v[rr] = fmaxf(v[rr], 0.f);
            }
            half4 hv = {(f16)v[0], (f16)v[1], (f16)v[2], (f16)v[3]};
            *(half4*)(Ch + (size_t)m * N + nb) = hv;
        }
    }
}

// --------------------------- MFMA GEMM (large) ----------------------------
// 256x256 tile, 8 waves (2Mx4N), per-wave 128x64. LDS 128KB, BK=64, dbuf.
template <bool RELU>
__global__ __launch_bounds__(512, 2) void k_mm8(const f16* __restrict__ A, const f16* __restrict__ BT,
                                                const float* __restrict__ bias, f16* __restrict__ Ch,
                                                int M, int N, int K, int nB, int nwg) {
    __shared__ f16 lsA[2][256 * 64];
    __shared__ f16 lsB[2][256 * 64];
    int wg = blockIdx.x;
    int q = nwg >> 3, r = nwg & 7;
    int xcd = wg & 7, lin = wg >> 3;
    int wgs = (xcd < r) ? (xcd * (q + 1) + lin) : (r * (q + 1) + (xcd - r) * q + lin);
    int bm = wgs / nB, bn = wgs % nB;

    int tid = threadIdx.x;
    int lane = tid & 63, wid = tid >> 6;
    int l16 = lane & 15, lhi = lane >> 4;
    int wm = (wid >> 2) * 128, wn = (wid & 3) * 64;
    int brow = bm * 256, bcol = bn * 256;

    v4f acc[8][4] = {};

    auto stageA = [&](int buf, int k0) {
#pragma unroll
        for (int it = 0; it < 4; ++it) {
            int b = it * 8192 + tid * 16;
            int row = b >> 7;
            int s = ((b >> 4) & 7) ^ (row & 7);
            gload_lds16(A + (size_t)(brow + row) * K + k0 + s * 8, ((char*)&lsA[buf][0]) + b);
        }
    };
    auto stageB = [&](int buf, int k0) {
#pragma unroll
        for (int it = 0; it < 4; ++it) {
            int b = it * 8192 + tid * 16;
            int row = b >> 7;
            int s = ((b >> 4) & 7) ^ (row & 7);
            gload_lds16(BT + (size_t)(bcol + row) * K + k0 + s * 8, ((char*)&lsB[buf][0]) + b);
        }
    };

    int nk = K >> 6;
    stageA(0, 0);
    stageB(0, 0);
    for (int kt = 0; kt < nk; ++kt) {
        int cur = kt & 1;
        __syncthreads();
        if (kt + 1 < nk) { stageA(cur ^ 1, (kt + 1) << 6); stageB(cur ^ 1, (kt + 1) << 6); }
#pragma unroll
        for (int ks = 0; ks < 2; ++ks) {
            half8 bf[4];
#pragma unroll
            for (int fn = 0; fn < 4; ++fn) {
                int row = wn + fn * 16 + l16;
                int sidx = (ks * 4 + lhi) ^ (row & 7);
                bf[fn] = *(const half8*)(&lsB[cur][0] + row * 64 + sidx * 8);
            }
#pragma unroll
            for (int fm = 0; fm < 8; ++fm) {
                int row = wm + fm * 16 + l16;
                int sidx = (ks * 4 + lhi) ^ (row & 7);
                half8 af = *(const half8*)(&lsA[cur][0] + row * 64 + sidx * 8);
#pragma unroll
                for (int fn = 0; fn < 4; ++fn)
                    acc[fm][fn] = __builtin_amdgcn_mfma_f32_16x16x32_f16(bf[fn], af, acc[fm][fn], 0, 0, 0);
            }
        }
    }
#pragma unroll
    for (int fm = 0; fm < 8; ++fm) {
        int m = brow + wm + fm * 16 + l16;
        if (m >= M) continue;
#pragma unroll
        for (int fn = 0; fn < 4; ++fn) {
            int nb = bcol + wn + fn * 16 + lhi * 4;
            v4f bv = *(const v4f*)(bias + nb);
            v4f v = acc[fm][fn] + bv;
            if (RELU) {
#pragma unroll
                for (int rr = 0; rr < 4; ++rr) v[rr] = fmaxf(v[rr], 0.f);
            }
            half4 hv = {(f16)v[0], (f16)v[1], (f16)v[2], (f16)v[3]};
            *(half4*)(Ch + (size_t)m * N + nb) = hv;
        }
    }
}

// ----------------------- fc2 GEMM + log_softmax ---------------------------
__global__ __launch_bounds__(256) void k_mmfc2(const f16* __restrict__ A, const f16* __restrict__ BT,
                                               const float* __restrict__ bias, float* __restrict__ out,
                                               int M, int K) {
    __shared__ f16 lsA[2][256 * 64];
    __shared__ f16 lsB[2][64 * 64];
    int bm = blockIdx.x;
    int tid = threadIdx.x;
    int lane = tid & 63, wid = tid >> 6;
    int l16 = lane & 15, lhi = lane >> 4;
    int wm = wid * 64;
    int brow = bm * 256;

    v4f acc[4][4] = {};

    auto stageA = [&](int buf, int k0) {
#pragma unroll
        for (int it = 0; it < 8; ++it) {
            int b = it * 4096 + tid * 16;
            int row = b >> 7;
            int s = ((b >> 4) & 7) ^ (row & 7);
            gload_lds16(A + (size_t)(brow + row) * K + k0 + s * 8, ((char*)&lsA[buf][0]) + b);
        }
    };
    auto stageB = [&](int buf, int k0) {
#pragma unroll
        for (int it = 0; it < 2; ++it) {
            int b = it * 4096 + tid * 16;
            int row = b >> 7;
            int s = ((b >> 4) & 7) ^ (row & 7);
            gload_lds16(BT + (size_t)row * K + k0 + s * 8, ((char*)&lsB[buf][0]) + b);
        }
    };

    int nk = K >> 6;
    stageA(0, 0);
    stageB(0, 0);
    for (int kt = 0; kt < nk; ++kt) {
        int cur = kt & 1;
        __syncthreads();
        if (kt + 1 < nk) { stageA(cur ^ 1, (kt + 1) << 6); stageB(cur ^ 1, (kt + 1) << 6); }
#pragma unroll
        for (int ks = 0; ks < 2; ++ks) {
            half8 bf[4];
#pragma unroll
            for (int fn = 0; fn < 4; ++fn) {
                int row = fn * 16 + l16;
                int sidx = (ks * 4 + lhi) ^ (row & 7);
                bf[fn] = *(const half8*)(&lsB[cur][0] + row * 64 + sidx * 8);
            }
#pragma unroll
            for (int fm = 0; fm < 4; ++fm) {
                int row = wm + fm * 16 + l16;
                int sidx = (ks * 4 + lhi) ^ (row & 7);
                half8 af = *(const half8*)(&lsA[cur][0] + row * 64 + sidx * 8);
#pragma unroll
                for (int fn = 0; fn < 4; ++fn)
                    acc[fm][fn] = __builtin_amdgcn_mfma_f32_16x16x32_f16(bf[fn], af, acc[fm][fn], 0, 0, 0);
            }
        }
    }

    float bv[4][4];
#pragma unroll
    for (int fn = 0; fn < 4; ++fn)
#pragma unroll
        for (int rr = 0; rr < 4; ++rr) {
            int nn = fn * 16 + lhi * 4 + rr;
            bv[fn][rr] = (nn < 40) ? bias[nn] : 0.f;
        }

#pragma unroll
    for (int fm = 0; fm < 4; ++fm) {
        int m = brow + wm + fm * 16 + l16;
        float v[4][4];
        float mx = -INFINITY;
#pragma unroll
        for (int fn = 0; fn < 4; ++fn)
#pragma unroll
            for (int rr = 0; rr < 4; ++rr) {
                int nn = fn * 16 + lhi * 4 + rr;
                v[fn][rr] = acc[fm][fn][rr] + bv[fn][rr];
                if (nn < 40) mx = fmaxf(mx, v[fn][rr]);
            }
        mx = fmaxf(mx, __shfl_xor(mx, 16));
        mx = fmaxf(mx, __shfl_xor(mx, 32));
        float s = 0.f;
#pragma unroll
        for (int fn = 0; fn < 3; ++fn)
#pragma unroll
            for (int rr = 0; rr < 4; ++rr) {
                int nn = fn * 16 + lhi * 4 + rr;
                if (nn < 40) s += __expf(v[fn][rr] - mx);
            }
        s += __shfl_xor(s, 16);
        s += __shfl_xor(s, 32);
        float ls = __logf(s);
        if (m < M) {
#pragma unroll
            for (int fn = 0; fn < 3; ++fn)
#pragma unroll
                for (int rr = 0; rr < 4; ++rr) {
                    int nn = fn * 16 + lhi * 4 + rr;
                    if (nn < 40) out[(size_t)m * 40 + nn] = v[fn][rr] - mx - ls;
                }
        }
    }
}

// ------------------------------ host --------------------------------------

extern "C" void kernel_launch(void* const* d_in, const int* in_sizes, int n_in,
                              void* d_out, int out_size, void* d_ws, size_t ws_size,
                              hipStream_t stream) {
    const float* x   = (const float*)d_in[0];
    const int*   ei  = (const int*)d_in[1];
    const float* ea  = (const float*)d_in[2];
    const float* W1  = (const float*)d_in[3];  const float* b1  = (const float*)d_in[4];
    const float* W2  = (const float*)d_in[5];  const float* b2  = (const float*)d_in[6];
    const float* W3  = (const float*)d_in[7];  const float* b3  = (const float*)d_in[8];
    const float* fW1 = (const float*)d_in[9];  const float* fb1 = (const float*)d_in[10];
    const float* fW2 = (const float*)d_in[11]; const float* fb2 = (const float*)d_in[12];

    int n = in_sizes[0] / 64;
    int E = in_sizes[1] / 2;
    int Mpad = ((n + 255) / 256) * 256;
    const int* src = ei;
    const int* dst = ei + E;
    float* out = (float*)d_out;

    char* p = (char*)d_ws;
    auto alloc = [&](size_t bytes) -> char* {
        char* r = p;
        p += (bytes + 255) & ~(size_t)255;
        return r;
    };
    int nb256 = (n + 255) / 256;
    u64*   packed4  = (u64*)alloc((size_t)n * 4 * 8);
    float* dinv     = (float*)alloc((size_t)n * 4);
    int*   cnt      = (int*)alloc((size_t)n * 4);
    int4*  rbase    = (int4*)alloc((size_t)n * 16);
    int*   rowptr   = (int*)alloc((size_t)(n + 1) * 4);
    int*   bsum     = (int*)alloc((size_t)nb256 * 4);
    int*   eslot    = (int*)alloc((size_t)E * 4);
    int*   csr_src  = (int*)alloc((size_t)E * 4);
    float* csr_norm = (float*)alloc((size_t)E * 4);
    f16* XH  = (f16*)alloc((size_t)Mpad * 64 * 2);
    f16* W1T = (f16*)alloc((size_t)128 * 64 * 2);
    f16* W2T = (f16*)alloc((size_t)256 * 128 * 2);
    f16* W3T = (f16*)alloc((size_t)512 * 256 * 2);
    f16* F1T = (f16*)alloc((size_t)512 * 512 * 2);
    f16* F2T = (f16*)alloc((size_t)64 * 512 * 2);
    f16* AGG = (f16*)alloc((size_t)Mpad * 256 * 2);
    f16* HA  = (f16*)alloc((size_t)Mpad * 512 * 2);
    f16* HB  = (f16*)alloc((size_t)Mpad * 512 * 2);

    const int tb = 256;
    int eB = (E + tb - 1) / tb;
    int e4B = (E / 4 + tb - 1) / tb + 1;
    auto aggB = [&](int npw) {
        long waves = (n + npw - 1) / npw;
        return (int)((waves * 64 + tb - 1) / tb);
    };

    // fused prep: packed4 init + x-cast + weight transposes (precedes edge1)
    {
        PrepArgs a;
        a.packed4 = packed4; a.n4 = n * 4;
        a.x = x; a.xh = XH; a.xt4 = n * 16;
        a.W[0] = W1;  a.WT[0] = W1T; a.lgK[0] = 6; a.N[0] = 128;
        a.W[1] = W2;  a.WT[1] = W2T; a.lgK[1] = 7; a.N[1] = 256;
        a.W[2] = W3;  a.WT[2] = W3T; a.lgK[2] = 8; a.N[2] = 512;
        a.W[3] = fW1; a.WT[3] = F1T; a.lgK[3] = 9; a.N[3] = 512;
        a.W[4] = fW2; a.WT[4] = F2T; a.lgK[4] = 9; a.N[4] = 40;
        a.off[0] = 0;
        a.off[1] = a.off[0] + 128 * 64;
        a.off[2] = a.off[1] + 256 * 128;
        a.off[3] = a.off[2] + 512 * 256;
        a.off[4] = a.off[3] + 512 * 512;
        a.off[5] = a.off[4] + 64 * 512;
        int tot = a.n4 + a.xt4 + a.off[5];
        k_prep<<<(tot + tb - 1) / tb, tb, 0, stream>>>(a);
    }

    // graph prep
    k_edge1<<<e4B, tb, 0, stream>>>(dst, ea, packed4, eslot, E, n);
    k_dinv_scan1<<<nb256, tb, 0, stream>>>(packed4, dinv, cnt, rbase, bsum, n);
    k_scan23<<<nb256, tb, 0, stream>>>(cnt, bsum, rowptr, n, E);
    k_fill<<<eB, tb, 0, stream>>>(src, dst, ea, eslot, dinv, rowptr, rbase, csr_src, csr_norm, E);

    auto mm8 = [&](const f16* a, const f16* bt, const float* bias, f16* ch, int N, int K) {
        int nB2 = N / 256;
        int nwg = (Mpad / 256) * nB2;
        k_mm8<true><<<nwg, 512, 0, stream>>>(a, bt, bias, ch, n, N, K, nB2, nwg);
    };

    // conv1: agg(xh)[.,64] -> @W1 relu -> HA[.,128]   (128x128 tile kernel)
    k_agg<64><<<aggB(8), tb, 0, stream>>>(XH, dinv, rowptr, csr_src, csr_norm, AGG, n);
    {
        int nwg = Mpad / 128;
        k_mm<true><<<nwg, 256, 0, stream>>>(AGG, W1T, b1, HA, n, 128, 64, 1, nwg);
    }
    // conv2: agg(HA)[.,128] -> @W2 relu -> HB[.,256]
    k_agg<128><<<aggB(4), tb, 0, stream>>>(HA, dinv, rowptr, csr_src, csr_norm, AGG, n);
    mm8(AGG, W2T, b2, HB, 256, 128);
    // conv3: agg(HB)[.,256] -> @W3 relu -> HA[.,512]
    k_agg<256><<<aggB(2), tb, 0, stream>>>(HB, dinv, rowptr, csr_src, csr_norm, AGG, n);
    mm8(AGG, W3T, b3, HA, 512, 256);
    // fc1: HA @ fW1 relu -> HB[.,512]
    mm8(HA, F1T, fb1, HB, 512, 512);
    // fc2 + log_softmax fused -> out
    k_mmfc2<<<Mpad / 256, 256, 0, stream>>>(HB, F2T, fb2, out, n, 512);
}

// Round 12
// 199.840 us; speedup vs baseline: 1.0305x; 1.0305x over previous
//
#include <hip/hip_runtime.h>
#include <cstdint>
#include <cstddef>

// ---------------------------------------------------------------------------
// GCN 3-conv + MLP head. FP16 single-product MFMA GEMMs (f32 accumulate),
// f16 activations, aggregate-before-linear (A(xW) == (Ax)W, Fin<Fout).
// All conv/fc GEMMs: 128x128 4-wave tiles (measured faster than 256x256 at
// the 2-barrier schedule: 912 vs 792 TF, + 2 blocks/CU barrier overlap).
// fc2 GEMM fuses bias + log_softmax. Planar-replicated packed u64 degree
// histogram; CSR slots from atomic returns; atomic-free fill.
// ---------------------------------------------------------------------------

typedef _Float16 f16;
typedef _Float16 half8 __attribute__((ext_vector_type(8)));
typedef _Float16 half4 __attribute__((ext_vector_type(4)));
typedef float v4f __attribute__((ext_vector_type(4)));
typedef unsigned long long u64;

__device__ inline void gload_lds16(const void* g, void* l) {
    __builtin_amdgcn_global_load_lds(
        (const __attribute__((address_space(1))) unsigned int*)g,
        (__attribute__((address_space(3))) unsigned int*)l, 16, 0, 0);
}

// ------------------------------ graph prep --------------------------------

// one packed atomic per edge into replica plane r=(e>>2)&3; old value -> slot
__global__ __launch_bounds__(256) void k_edge1(const int* __restrict__ dst, const float* __restrict__ ew,
                                               u64* __restrict__ packed4, int* __restrict__ eslot,
                                               int E, int n) {
    int t = blockIdx.x * blockDim.x + threadIdx.x;
    int e0 = t * 4;
    int r = t & 3;
    u64* plane = packed4 + (size_t)r * n;
    if (e0 + 3 < E) {
        int4 d4 = *(const int4*)(dst + e0);
        float4 w4 = *(const float4*)(ew + e0);
        u64 a0 = ((u64)__float2uint_rn(w4.x * 1048576.f) << 24) | 1ULL;
        u64 a1 = ((u64)__float2uint_rn(w4.y * 1048576.f) << 24) | 1ULL;
        u64 a2 = ((u64)__float2uint_rn(w4.z * 1048576.f) << 24) | 1ULL;
        u64 a3 = ((u64)__float2uint_rn(w4.w * 1048576.f) << 24) | 1ULL;
        u64 o0 = atomicAdd(&plane[d4.x], a0);
        u64 o1 = atomicAdd(&plane[d4.y], a1);
        u64 o2 = atomicAdd(&plane[d4.z], a2);
        u64 o3 = atomicAdd(&plane[d4.w], a3);
        int4 s;
        s.x = (int)(o0 & 0xFFFFFF); s.y = (int)(o1 & 0xFFFFFF);
        s.z = (int)(o2 & 0xFFFFFF); s.w = (int)(o3 & 0xFFFFFF);
        *(int4*)(eslot + e0) = s;
    } else {
        for (int e = e0; e < E; ++e) {
            u64 a = ((u64)__float2uint_rn(ew[e] * 1048576.f) << 24) | 1ULL;
            u64 o = atomicAdd(&plane[dst[e]], a);
            eslot[e] = (int)(o & 0xFFFFFF);
        }
    }
}

// fused: unpack 4 planes -> dinv + per-replica bases + per-block cnt sums
__global__ __launch_bounds__(256) void k_dinv_scan1(const u64* __restrict__ packed4,
                                                    float* __restrict__ dinv, int* __restrict__ cnt,
                                                    int4* __restrict__ rbase, int* __restrict__ bsum, int n) {
    int i = blockIdx.x * 256 + threadIdx.x;
    int c = 0;
    if (i < n) {
        u64 p0 = packed4[i];
        u64 p1 = packed4[(size_t)n + i];
        u64 p2 = packed4[(size_t)2 * n + i];
        u64 p3 = packed4[(size_t)3 * n + i];
        int c0 = (int)(p0 & 0xFFFFFF), c1 = (int)(p1 & 0xFFFFFF);
        int c2 = (int)(p2 & 0xFFFFFF), c3 = (int)(p3 & 0xFFFFFF);
        c = c0 + c1 + c2 + c3;
        rbase[i] = make_int4(0, c0, c0 + c1, c0 + c1 + c2);
        float d = 1.0f + (float)((p0 >> 24) + (p1 >> 24) + (p2 >> 24) + (p3 >> 24)) * (1.0f / 1048576.f);
        float r = rsqrtf(d);
        r = r * (1.5f - 0.5f * d * r * r);
        dinv[i] = r;
        cnt[i] = c;
    }
    int v = c;
#pragma unroll
    for (int o = 32; o; o >>= 1) v += __shfl_xor(v, o);
    __shared__ int s[4];
    if ((threadIdx.x & 63) == 0) s[threadIdx.x >> 6] = v;
    __syncthreads();
    if (threadIdx.x == 0) bsum[blockIdx.x] = s[0] + s[1] + s[2] + s[3];
}

// 256-thread inclusive block scan (shfl wave scan + LDS wave offsets).
__device__ inline int block_scan_incl(int v) {
    __shared__ int ws[4];
    int lane = threadIdx.x & 63, w = threadIdx.x >> 6;
#pragma unroll
    for (int off = 1; off < 64; off <<= 1) {
        int t = __shfl_up(v, off);
        if (lane >= off) v += t;
    }
    if (lane == 63) ws[w] = v;
    __syncthreads();
    int add = 0;
#pragma unroll
    for (int i = 0; i < 4; ++i) add += (i < w) ? ws[i] : 0;
    __syncthreads();
    return v + add;
}

// fused scan2+scan3: each block sums bsum[0..blk) itself (one wave), then
// local scan + offset -> rowptr. No inter-block communication.
__global__ __launch_bounds__(256) void k_scan23(const int* __restrict__ cnt, const int* __restrict__ bsum,
                                                int* __restrict__ rowptr, int n, int E) {
    int blk = blockIdx.x, tid = threadIdx.x;
    int i = blk * 256 + tid;
    __shared__ int spre;
    if (tid < 64) {
        int s = 0;
        for (int j = tid; j < blk; j += 64) s += bsum[j];
#pragma unroll
        for (int o = 32; o; o >>= 1) s += __shfl_xor(s, o);
        if (tid == 0) spre = s;
    }
    __syncthreads();
    int v = (i < n) ? cnt[i] : 0;
    int incl = block_scan_incl(v);
    if (i < n) rowptr[i] = spre + incl - v;
    if (i == n - 1) rowptr[n] = E;
}

// atomic-free CSR fill using precomputed slots + replica bases
__global__ __launch_bounds__(256) void k_fill(const int* __restrict__ src, const int* __restrict__ dst,
                                              const float* __restrict__ ew, const int* __restrict__ eslot,
                                              const float* __restrict__ dinv, const int* __restrict__ rowptr,
                                              const int4* __restrict__ rbase,
                                              int* __restrict__ csr_src, float* __restrict__ csr_norm, int E) {
    int e = blockIdx.x * blockDim.x + threadIdx.x;
    if (e < E) {
        int d = dst[e], s = src[e];
        int r = (e >> 2) & 3;
        int4 rb = rbase[d];
        int base = (r == 0) ? rb.x : (r == 1) ? rb.y : (r == 2) ? rb.z : rb.w;
        int idx = rowptr[d] + base + eslot[e];
        csr_src[idx] = s;
        csr_norm[idx] = dinv[s] * ew[e] * dinv[d];
    }
}

// fused: packed4 init + x f32->f16 cast + 5 weight transposes W[K,N]->WT[Np,K]
struct PrepArgs {
    u64* packed4; int n4;
    const float* x; f16* xh; int xt4;
    const float* W[5]; f16* WT[5];
    int lgK[5]; int N[5]; int off[6];
};
__global__ __launch_bounds__(256) void k_prep(PrepArgs a) {
    int i = blockIdx.x * 256 + threadIdx.x;
    if (i < a.n4) { a.packed4[i] = 0ULL; return; }
    int j = i - a.n4;
    if (j < a.xt4) {
        float4 v = *(const float4*)(a.x + (size_t)j * 4);
        half4 h = {(f16)v.x, (f16)v.y, (f16)v.z, (f16)v.w};
        *(half4*)(a.xh + (size_t)j * 4) = h;
        return;
    }
    int w = j - a.xt4;
#pragma unroll
    for (int s = 0; s < 5; ++s) {
        if (w >= a.off[s] && w < a.off[s + 1]) {
            int li = w - a.off[s];
            int K = 1 << a.lgK[s];
            int nr = li >> a.lgK[s], k = li & (K - 1);
            float v = (nr < a.N[s]) ? a.W[s][(size_t)k * a.N[s] + nr] : 0.f;
            a.WT[s][li] = (f16)v;
        }
    }
}

// ------------------------------ aggregation -------------------------------
// out[i,:] = dinv[i]^2*h[i,:] + sum_j norm_j*h[src_j,:]; f16 in/out, f32 acc.
template <int F>
__global__ __launch_bounds__(256) void k_agg(const f16* __restrict__ h,
                                             const float* __restrict__ dinv, const int* __restrict__ rowptr,
                                             const int* __restrict__ csr_src, const float* __restrict__ csr_norm,
                                             f16* __restrict__ o, int n) {
    constexpr int LPN = F / 8;
    constexpr int NPW = 64 / LPN;
    int wave = (int)((blockIdx.x * (unsigned)blockDim.x + threadIdx.x) >> 6);
    int lane = threadIdx.x & 63;
    int grp = lane / LPN, lin = lane % LPN;
    int node = wave * NPW + grp;
    if (node >= n) return;
    float di = dinv[node], w0 = di * di;
    float acc[8];
#pragma unroll
    for (int i = 0; i < 8; ++i) acc[i] = 0.f;

    auto gat = [&](int s, float w) {
        half8 x = *(const half8*)(h + (size_t)s * F + lin * 8);
#pragma unroll
        for (int i = 0; i < 8; ++i) acc[i] += w * (float)x[i];
    };

    gat(node, w0);
    int beg = rowptr[node], end = rowptr[node + 1];
    int j = beg;
    for (; j + 3 < end; j += 4) {  // 4 independent gathers in flight
        int s0 = csr_src[j], s1 = csr_src[j + 1], s2 = csr_src[j + 2], s3 = csr_src[j + 3];
        float u0 = csr_norm[j], u1 = csr_norm[j + 1], u2 = csr_norm[j + 2], u3 = csr_norm[j + 3];
        gat(s0, u0); gat(s1, u1); gat(s2, u2); gat(s3, u3);
    }
    for (; j < end; ++j) gat(csr_src[j], csr_norm[j]);

    half8 v;
#pragma unroll
    for (int i = 0; i < 8; ++i) v[i] = (f16)acc[i];
    *(half8*)(o + (size_t)node * F + (size_t)lin * 8) = v;
}

// ------------------------------ MFMA GEMM ----------------------------------
// 128x128 tile, 4 waves 2x2. A,B via global_load_lds (XOR-swizzled both
// sides), double-buffered, one barrier per k-step. 64KB LDS -> 2 blocks/CU.
// Operand-swapped MFMA -> C^T frags -> coalesced 8B stores.
template <bool RELU>
__global__ __launch_bounds__(256) void k_mm(const f16* __restrict__ A, const f16* __restrict__ BT,
                                            const float* __restrict__ bias, f16* __restrict__ Ch,
                                            int M, int N, int K, int nB, int nwg) {
    __shared__ f16 lsA[2][128 * 64];
    __shared__ f16 lsB[2][128 * 64];
    int wg = blockIdx.x;
    int q = nwg >> 3, r = nwg & 7;
    int xcd = wg & 7, lin = wg >> 3;
    int wgs = (xcd < r) ? (xcd * (q + 1) + lin) : (r * (q + 1) + (xcd - r) * q + lin);
    int bm = wgs / nB, bn = wgs % nB;

    int tid = threadIdx.x;
    int lane = tid & 63, wid = tid >> 6;
    int l16 = lane & 15, lhi = lane >> 4;
    int wm = (wid >> 1) * 64, wn = (wid & 1) * 64;
    int brow = bm * 128, bcol = bn * 128;

    v4f acc[4][4] = {};

    auto stageA = [&](int buf, int k0) {
#pragma unroll
        for (int it = 0; it < 4; ++it) {
            int b = it * 4096 + tid * 16;
            int row = b >> 7;
            int s = ((b >> 4) & 7) ^ (row & 7);
            gload_lds16(A + (size_t)(brow + row) * K + k0 + s * 8, ((char*)&lsA[buf][0]) + b);
        }
    };
    auto stageB = [&](int buf, int k0) {
#pragma unroll
        for (int it = 0; it < 4; ++it) {
            int b = it * 4096 + tid * 16;
            int row = b >> 7;
            int s = ((b >> 4) & 7) ^ (row & 7);
            gload_lds16(BT + (size_t)(bcol + row) * K + k0 + s * 8, ((char*)&lsB[buf][0]) + b);
        }
    };

    int nk = K >> 6;
    stageA(0, 0);
    stageB(0, 0);
    for (int kt = 0; kt < nk; ++kt) {
        int cur = kt & 1;
        __syncthreads();  // buf[cur] DMA drained; prior LDS reads done
        if (kt + 1 < nk) { stageA(cur ^ 1, (kt + 1) << 6); stageB(cur ^ 1, (kt + 1) << 6); }
#pragma unroll
        for (int ks = 0; ks < 2; ++ks) {
            half8 bf[4];
#pragma unroll
            for (int fn = 0; fn < 4; ++fn) {
                int row = wn + fn * 16 + l16;
                int sidx = (ks * 4 + lhi) ^ (row & 7);
                bf[fn] = *(const half8*)(&lsB[cur][0] + row * 64 + sidx * 8);
            }
#pragma unroll
            for (int fm = 0; fm < 4; ++fm) {
                int row = wm + fm * 16 + l16;
                int sidx = (ks * 4 + lhi) ^ (row & 7);
                half8 af = *(const half8*)(&lsA[cur][0] + row * 64 + sidx * 8);
#pragma unroll
                for (int fn = 0; fn < 4; ++fn)
                    acc[fm][fn] = __builtin_amdgcn_mfma_f32_16x16x32_f16(bf[fn], af, acc[fm][fn], 0, 0, 0);
            }
        }
    }
#pragma unroll
    for (int fm = 0; fm < 4; ++fm) {
        int m = brow + wm + fm * 16 + l16;
        if (m >= M) continue;
#pragma unroll
        for (int fn = 0; fn < 4; ++fn) {
            int nb = bcol + wn + fn * 16 + lhi * 4;
            v4f bv = *(const v4f*)(bias + nb);
            v4f v = acc[fm][fn] + bv;
            if (RELU) {
#pragma unroll
                for (int rr = 0; rr < 4; ++rr) v[rr] = fmaxf(v[rr], 0.f);
            }
            half4 hv = {(f16)v[0], (f16)v[1], (f16)v[2], (f16)v[3]};
            *(half4*)(Ch + (size_t)m * N + nb) = hv;
        }
    }
}

// ----------------------- fc2 GEMM + log_softmax ---------------------------
__global__ __launch_bounds__(256) void k_mmfc2(const f16* __restrict__ A, const f16* __restrict__ BT,
                                               const float* __restrict__ bias, float* __restrict__ out,
                                               int M, int K) {
    __shared__ f16 lsA[2][256 * 64];
    __shared__ f16 lsB[2][64 * 64];
    int bm = blockIdx.x;
    int tid = threadIdx.x;
    int lane = tid & 63, wid = tid >> 6;
    int l16 = lane & 15, lhi = lane >> 4;
    int wm = wid * 64;
    int brow = bm * 256;

    v4f acc[4][4] = {};

    auto stageA = [&](int buf, int k0) {
#pragma unroll
        for (int it = 0; it < 8; ++it) {
            int b = it * 4096 + tid * 16;
            int row = b >> 7;
            int s = ((b >> 4) & 7) ^ (row & 7);
            gload_lds16(A + (size_t)(brow + row) * K + k0 + s * 8, ((char*)&lsA[buf][0]) + b);
        }
    };
    auto stageB = [&](int buf, int k0) {
#pragma unroll
        for (int it = 0; it < 2; ++it) {
            int b = it * 4096 + tid * 16;
            int row = b >> 7;
            int s = ((b >> 4) & 7) ^ (row & 7);
            gload_lds16(BT + (size_t)row * K + k0 + s * 8, ((char*)&lsB[buf][0]) + b);
        }
    };

    int nk = K >> 6;
    stageA(0, 0);
    stageB(0, 0);
    for (int kt = 0; kt < nk; ++kt) {
        int cur = kt & 1;
        __syncthreads();
        if (kt + 1 < nk) { stageA(cur ^ 1, (kt + 1) << 6); stageB(cur ^ 1, (kt + 1) << 6); }
#pragma unroll
        for (int ks = 0; ks < 2; ++ks) {
            half8 bf[4];
#pragma unroll
            for (int fn = 0; fn < 4; ++fn) {
                int row = fn * 16 + l16;
                int sidx = (ks * 4 + lhi) ^ (row & 7);
                bf[fn] = *(const half8*)(&lsB[cur][0] + row * 64 + sidx * 8);
            }
#pragma unroll
            for (int fm = 0; fm < 4; ++fm) {
                int row = wm + fm * 16 + l16;
                int sidx = (ks * 4 + lhi) ^ (row & 7);
                half8 af = *(const half8*)(&lsA[cur][0] + row * 64 + sidx * 8);
#pragma unroll
                for (int fn = 0; fn < 4; ++fn)
                    acc[fm][fn] = __builtin_amdgcn_mfma_f32_16x16x32_f16(bf[fn], af, acc[fm][fn], 0, 0, 0);
            }
        }
    }

    float bv[4][4];
#pragma unroll
    for (int fn = 0; fn < 4; ++fn)
#pragma unroll
        for (int rr = 0; rr < 4; ++rr) {
            int nn = fn * 16 + lhi * 4 + rr;
            bv[fn][rr] = (nn < 40) ? bias[nn] : 0.f;
        }

#pragma unroll
    for (int fm = 0; fm < 4; ++fm) {
        int m = brow + wm + fm * 16 + l16;
        float v[4][4];
        float mx = -INFINITY;
#pragma unroll
        for (int fn = 0; fn < 4; ++fn)
#pragma unroll
            for (int rr = 0; rr < 4; ++rr) {
                int nn = fn * 16 + lhi * 4 + rr;
                v[fn][rr] = acc[fm][fn][rr] + bv[fn][rr];
                if (nn < 40) mx = fmaxf(mx, v[fn][rr]);
            }
        mx = fmaxf(mx, __shfl_xor(mx, 16));
        mx = fmaxf(mx, __shfl_xor(mx, 32));
        float s = 0.f;
#pragma unroll
        for (int fn = 0; fn < 3; ++fn)
#pragma unroll
            for (int rr = 0; rr < 4; ++rr) {
                int nn = fn * 16 + lhi * 4 + rr;
                if (nn < 40) s += __expf(v[fn][rr] - mx);
            }
        s += __shfl_xor(s, 16);
        s += __shfl_xor(s, 32);
        float ls = __logf(s);
        if (m < M) {
#pragma unroll
            for (int fn = 0; fn < 3; ++fn)
#pragma unroll
                for (int rr = 0; rr < 4; ++rr) {
                    int nn = fn * 16 + lhi * 4 + rr;
                    if (nn < 40) out[(size_t)m * 40 + nn] = v[fn][rr] - mx - ls;
                }
        }
    }
}

// ------------------------------ host --------------------------------------

extern "C" void kernel_launch(void* const* d_in, const int* in_sizes, int n_in,
                              void* d_out, int out_size, void* d_ws, size_t ws_size,
                              hipStream_t stream) {
    const float* x   = (const float*)d_in[0];
    const int*   ei  = (const int*)d_in[1];
    const float* ea  = (const float*)d_in[2];
    const float* W1  = (const float*)d_in[3];  const float* b1  = (const float*)d_in[4];
    const float* W2  = (const float*)d_in[5];  const float* b2  = (const float*)d_in[6];
    const float* W3  = (const float*)d_in[7];  const float* b3  = (const float*)d_in[8];
    const float* fW1 = (const float*)d_in[9];  const float* fb1 = (const float*)d_in[10];
    const float* fW2 = (const float*)d_in[11]; const float* fb2 = (const float*)d_in[12];

    int n = in_sizes[0] / 64;
    int E = in_sizes[1] / 2;
    int Mpad = ((n + 255) / 256) * 256;
    const int* src = ei;
    const int* dst = ei + E;
    float* out = (float*)d_out;

    char* p = (char*)d_ws;
    auto alloc = [&](size_t bytes) -> char* {
        char* r = p;
        p += (bytes + 255) & ~(size_t)255;
        return r;
    };
    int nb256 = (n + 255) / 256;
    u64*   packed4  = (u64*)alloc((size_t)n * 4 * 8);
    float* dinv     = (float*)alloc((size_t)n * 4);
    int*   cnt      = (int*)alloc((size_t)n * 4);
    int4*  rbase    = (int4*)alloc((size_t)n * 16);
    int*   rowptr   = (int*)alloc((size_t)(n + 1) * 4);
    int*   bsum     = (int*)alloc((size_t)nb256 * 4);
    int*   eslot    = (int*)alloc((size_t)E * 4);
    int*   csr_src  = (int*)alloc((size_t)E * 4);
    float* csr_norm = (float*)alloc((size_t)E * 4);
    f16* XH  = (f16*)alloc((size_t)Mpad * 64 * 2);
    f16* W1T = (f16*)alloc((size_t)128 * 64 * 2);
    f16* W2T = (f16*)alloc((size_t)256 * 128 * 2);
    f16* W3T = (f16*)alloc((size_t)512 * 256 * 2);
    f16* F1T = (f16*)alloc((size_t)512 * 512 * 2);
    f16* F2T = (f16*)alloc((size_t)64 * 512 * 2);
    f16* AGG = (f16*)alloc((size_t)Mpad * 256 * 2);
    f16* HA  = (f16*)alloc((size_t)Mpad * 512 * 2);
    f16* HB  = (f16*)alloc((size_t)Mpad * 512 * 2);

    const int tb = 256;
    int eB = (E + tb - 1) / tb;
    int e4B = (E / 4 + tb - 1) / tb + 1;
    auto aggB = [&](int npw) {
        long waves = (n + npw - 1) / npw;
        return (int)((waves * 64 + tb - 1) / tb);
    };

    // fused prep: packed4 init + x-cast + weight transposes (precedes edge1)
    {
        PrepArgs a;
        a.packed4 = packed4; a.n4 = n * 4;
        a.x = x; a.xh = XH; a.xt4 = n * 16;
        a.W[0] = W1;  a.WT[0] = W1T; a.lgK[0] = 6; a.N[0] = 128;
        a.W[1] = W2;  a.WT[1] = W2T; a.lgK[1] = 7; a.N[1] = 256;
        a.W[2] = W3;  a.WT[2] = W3T; a.lgK[2] = 8; a.N[2] = 512;
        a.W[3] = fW1; a.WT[3] = F1T; a.lgK[3] = 9; a.N[3] = 512;
        a.W[4] = fW2; a.WT[4] = F2T; a.lgK[4] = 9; a.N[4] = 40;
        a.off[0] = 0;
        a.off[1] = a.off[0] + 128 * 64;
        a.off[2] = a.off[1] + 256 * 128;
        a.off[3] = a.off[2] + 512 * 256;
        a.off[4] = a.off[3] + 512 * 512;
        a.off[5] = a.off[4] + 64 * 512;
        int tot = a.n4 + a.xt4 + a.off[5];
        k_prep<<<(tot + tb - 1) / tb, tb, 0, stream>>>(a);
    }

    // graph prep
    k_edge1<<<e4B, tb, 0, stream>>>(dst, ea, packed4, eslot, E, n);
    k_dinv_scan1<<<nb256, tb, 0, stream>>>(packed4, dinv, cnt, rbase, bsum, n);
    k_scan23<<<nb256, tb, 0, stream>>>(cnt, bsum, rowptr, n, E);
    k_fill<<<eB, tb, 0, stream>>>(src, dst, ea, eslot, dinv, rowptr, rbase, csr_src, csr_norm, E);

    // 128x128-tile GEMM for all conv/fc layers
    auto mm = [&](const f16* a, const f16* bt, const float* bias, f16* ch, int N, int K) {
        int nB2 = N / 128;
        int nwg = (Mpad / 128) * nB2;
        k_mm<true><<<nwg, 256, 0, stream>>>(a, bt, bias, ch, n, N, K, nB2, nwg);
    };

    // conv1: agg(xh)[.,64] -> @W1 relu -> HA[.,128]
    k_agg<64><<<aggB(8), tb, 0, stream>>>(XH, dinv, rowptr, csr_src, csr_norm, AGG, n);
    mm(AGG, W1T, b1, HA, 128, 64);
    // conv2: agg(HA)[.,128] -> @W2 relu -> HB[.,256]
    k_agg<128><<<aggB(4), tb, 0, stream>>>(HA, dinv, rowptr, csr_src, csr_norm, AGG, n);
    mm(AGG, W2T, b2, HB, 256, 128);
    // conv3: agg(HB)[.,256] -> @W3 relu -> HA[.,512]
    k_agg<256><<<aggB(2), tb, 0, stream>>>(HB, dinv, rowptr, csr_src, csr_norm, AGG, n);
    mm(AGG, W3T, b3, HA, 512, 256);
    // fc1: HA @ fW1 relu -> HB[.,512]
    mm(HA, F1T, fb1, HB, 512, 512);
    // fc2 + log_softmax fused -> out
    k_mmfc2<<<Mpad / 256, 256, 0, stream>>>(HB, F2T, fb2, out, n, 512);
}

// Round 13
// 199.084 us; speedup vs baseline: 1.0344x; 1.0038x over previous
//
#include <hip/hip_runtime.h>
#include <cstdint>
#include <cstddef>

// ---------------------------------------------------------------------------
// GCN 3-conv + MLP head. FP16 single-product MFMA GEMMs (f32 accumulate),
// f16 activations, aggregate-before-linear (A(xW) == (Ax)W, Fin<Fout).
// All conv/fc GEMMs: 128x128 4-wave tiles. fc2 GEMM fuses bias+log_softmax.
// Planar-replicated packed u64 degree histogram; CSR slots from atomic
// returns; atomic-free fill. Round 13: coalesced-read weight transpose
// (strided f16 writes merge in L2) + f16 csr_norm.
// ---------------------------------------------------------------------------

typedef _Float16 f16;
typedef _Float16 half8 __attribute__((ext_vector_type(8)));
typedef _Float16 half4 __attribute__((ext_vector_type(4)));
typedef float v4f __attribute__((ext_vector_type(4)));
typedef unsigned long long u64;

__device__ inline void gload_lds16(const void* g, void* l) {
    __builtin_amdgcn_global_load_lds(
        (const __attribute__((address_space(1))) unsigned int*)g,
        (__attribute__((address_space(3))) unsigned int*)l, 16, 0, 0);
}

// ------------------------------ graph prep --------------------------------

// one packed atomic per edge into replica plane r=(e>>2)&3; old value -> slot
__global__ __launch_bounds__(256) void k_edge1(const int* __restrict__ dst, const float* __restrict__ ew,
                                               u64* __restrict__ packed4, int* __restrict__ eslot,
                                               int E, int n) {
    int t = blockIdx.x * blockDim.x + threadIdx.x;
    int e0 = t * 4;
    int r = t & 3;
    u64* plane = packed4 + (size_t)r * n;
    if (e0 + 3 < E) {
        int4 d4 = *(const int4*)(dst + e0);
        float4 w4 = *(const float4*)(ew + e0);
        u64 a0 = ((u64)__float2uint_rn(w4.x * 1048576.f) << 24) | 1ULL;
        u64 a1 = ((u64)__float2uint_rn(w4.y * 1048576.f) << 24) | 1ULL;
        u64 a2 = ((u64)__float2uint_rn(w4.z * 1048576.f) << 24) | 1ULL;
        u64 a3 = ((u64)__float2uint_rn(w4.w * 1048576.f) << 24) | 1ULL;
        u64 o0 = atomicAdd(&plane[d4.x], a0);
        u64 o1 = atomicAdd(&plane[d4.y], a1);
        u64 o2 = atomicAdd(&plane[d4.z], a2);
        u64 o3 = atomicAdd(&plane[d4.w], a3);
        int4 s;
        s.x = (int)(o0 & 0xFFFFFF); s.y = (int)(o1 & 0xFFFFFF);
        s.z = (int)(o2 & 0xFFFFFF); s.w = (int)(o3 & 0xFFFFFF);
        *(int4*)(eslot + e0) = s;
    } else {
        for (int e = e0; e < E; ++e) {
            u64 a = ((u64)__float2uint_rn(ew[e] * 1048576.f) << 24) | 1ULL;
            u64 o = atomicAdd(&plane[dst[e]], a);
            eslot[e] = (int)(o & 0xFFFFFF);
        }
    }
}

// fused: unpack 4 planes -> dinv + per-replica bases + per-block cnt sums
__global__ __launch_bounds__(256) void k_dinv_scan1(const u64* __restrict__ packed4,
                                                    float* __restrict__ dinv, int* __restrict__ cnt,
                                                    int4* __restrict__ rbase, int* __restrict__ bsum, int n) {
    int i = blockIdx.x * 256 + threadIdx.x;
    int c = 0;
    if (i < n) {
        u64 p0 = packed4[i];
        u64 p1 = packed4[(size_t)n + i];
        u64 p2 = packed4[(size_t)2 * n + i];
        u64 p3 = packed4[(size_t)3 * n + i];
        int c0 = (int)(p0 & 0xFFFFFF), c1 = (int)(p1 & 0xFFFFFF);
        int c2 = (int)(p2 & 0xFFFFFF), c3 = (int)(p3 & 0xFFFFFF);
        c = c0 + c1 + c2 + c3;
        rbase[i] = make_int4(0, c0, c0 + c1, c0 + c1 + c2);
        float d = 1.0f + (float)((p0 >> 24) + (p1 >> 24) + (p2 >> 24) + (p3 >> 24)) * (1.0f / 1048576.f);
        float r = rsqrtf(d);
        r = r * (1.5f - 0.5f * d * r * r);
        dinv[i] = r;
        cnt[i] = c;
    }
    int v = c;
#pragma unroll
    for (int o = 32; o; o >>= 1) v += __shfl_xor(v, o);
    __shared__ int s[4];
    if ((threadIdx.x & 63) == 0) s[threadIdx.x >> 6] = v;
    __syncthreads();
    if (threadIdx.x == 0) bsum[blockIdx.x] = s[0] + s[1] + s[2] + s[3];
}

// 256-thread inclusive block scan (shfl wave scan + LDS wave offsets).
__device__ inline int block_scan_incl(int v) {
    __shared__ int ws[4];
    int lane = threadIdx.x & 63, w = threadIdx.x >> 6;
#pragma unroll
    for (int off = 1; off < 64; off <<= 1) {
        int t = __shfl_up(v, off);
        if (lane >= off) v += t;
    }
    if (lane == 63) ws[w] = v;
    __syncthreads();
    int add = 0;
#pragma unroll
    for (int i = 0; i < 4; ++i) add += (i < w) ? ws[i] : 0;
    __syncthreads();
    return v + add;
}

// fused scan2+scan3: each block sums bsum[0..blk) itself (one wave), then
// local scan + offset -> rowptr. No inter-block communication.
__global__ __launch_bounds__(256) void k_scan23(const int* __restrict__ cnt, const int* __restrict__ bsum,
                                                int* __restrict__ rowptr, int n, int E) {
    int blk = blockIdx.x, tid = threadIdx.x;
    int i = blk * 256 + tid;
    __shared__ int spre;
    if (tid < 64) {
        int s = 0;
        for (int j = tid; j < blk; j += 64) s += bsum[j];
#pragma unroll
        for (int o = 32; o; o >>= 1) s += __shfl_xor(s, o);
        if (tid == 0) spre = s;
    }
    __syncthreads();
    int v = (i < n) ? cnt[i] : 0;
    int incl = block_scan_incl(v);
    if (i < n) rowptr[i] = spre + incl - v;
    if (i == n - 1) rowptr[n] = E;
}

// atomic-free CSR fill using precomputed slots + replica bases; f16 norm
__global__ __launch_bounds__(256) void k_fill(const int* __restrict__ src, const int* __restrict__ dst,
                                              const float* __restrict__ ew, const int* __restrict__ eslot,
                                              const float* __restrict__ dinv, const int* __restrict__ rowptr,
                                              const int4* __restrict__ rbase,
                                              int* __restrict__ csr_src, f16* __restrict__ csr_norm, int E) {
    int e = blockIdx.x * blockDim.x + threadIdx.x;
    if (e < E) {
        int d = dst[e], s = src[e];
        int r = (e >> 2) & 3;
        int4 rb = rbase[d];
        int base = (r == 0) ? rb.x : (r == 1) ? rb.y : (r == 2) ? rb.z : rb.w;
        int idx = rowptr[d] + base + eslot[e];
        csr_src[idx] = s;
        csr_norm[idx] = (f16)(dinv[s] * ew[e] * dinv[d]);
    }
}

// fused: packed4 init + x f32->f16 cast + 5 weight transposes W[K,N]->WT[Np,K].
// Transpose reads COALESCED (thread i in segment: k=li/Np, nr=li%Np ->
// consecutive threads read consecutive nr); strided f16 writes merge in L2.
struct PrepArgs {
    u64* packed4; int n4;
    const float* x; f16* xh; int xt4;
    const float* W[5]; f16* WT[5];
    int lgK[5]; int lgNp[5]; int N[5]; int off[6];
};
__global__ __launch_bounds__(256) void k_prep(PrepArgs a) {
    int i = blockIdx.x * 256 + threadIdx.x;
    if (i < a.n4) { a.packed4[i] = 0ULL; return; }
    int j = i - a.n4;
    if (j < a.xt4) {
        float4 v = *(const float4*)(a.x + (size_t)j * 4);
        half4 h = {(f16)v.x, (f16)v.y, (f16)v.z, (f16)v.w};
        *(half4*)(a.xh + (size_t)j * 4) = h;
        return;
    }
    int w = j - a.xt4;
#pragma unroll
    for (int s = 0; s < 5; ++s) {
        if (w >= a.off[s] && w < a.off[s + 1]) {
            int li = w - a.off[s];
            int Np = 1 << a.lgNp[s];
            int K = 1 << a.lgK[s];
            int k = li >> a.lgNp[s], nr = li & (Np - 1);
            float v = (nr < a.N[s]) ? a.W[s][(size_t)k * a.N[s] + nr] : 0.f;
            a.WT[s][(size_t)nr * K + k] = (f16)v;
        }
    }
}

// ------------------------------ aggregation -------------------------------
// out[i,:] = dinv[i]^2*h[i,:] + sum_j norm_j*h[src_j,:]; f16 in/out, f32 acc.
template <int F>
__global__ __launch_bounds__(256) void k_agg(const f16* __restrict__ h,
                                             const float* __restrict__ dinv, const int* __restrict__ rowptr,
                                             const int* __restrict__ csr_src, const f16* __restrict__ csr_norm,
                                             f16* __restrict__ o, int n) {
    constexpr int LPN = F / 8;
    constexpr int NPW = 64 / LPN;
    int wave = (int)((blockIdx.x * (unsigned)blockDim.x + threadIdx.x) >> 6);
    int lane = threadIdx.x & 63;
    int grp = lane / LPN, lin = lane % LPN;
    int node = wave * NPW + grp;
    if (node >= n) return;
    float di = dinv[node], w0 = di * di;
    float acc[8];
#pragma unroll
    for (int i = 0; i < 8; ++i) acc[i] = 0.f;

    auto gat = [&](int s, float w) {
        half8 x = *(const half8*)(h + (size_t)s * F + lin * 8);
#pragma unroll
        for (int i = 0; i < 8; ++i) acc[i] += w * (float)x[i];
    };

    gat(node, w0);
    int beg = rowptr[node], end = rowptr[node + 1];
    int j = beg;
    for (; j + 3 < end; j += 4) {  // 4 independent gathers in flight
        int s0 = csr_src[j], s1 = csr_src[j + 1], s2 = csr_src[j + 2], s3 = csr_src[j + 3];
        float u0 = (float)csr_norm[j], u1 = (float)csr_norm[j + 1];
        float u2 = (float)csr_norm[j + 2], u3 = (float)csr_norm[j + 3];
        gat(s0, u0); gat(s1, u1); gat(s2, u2); gat(s3, u3);
    }
    for (; j < end; ++j) gat(csr_src[j], (float)csr_norm[j]);

    half8 v;
#pragma unroll
    for (int i = 0; i < 8; ++i) v[i] = (f16)acc[i];
    *(half8*)(o + (size_t)node * F + (size_t)lin * 8) = v;
}

// ------------------------------ MFMA GEMM ----------------------------------
// 128x128 tile, 4 waves 2x2. A,B via global_load_lds (XOR-swizzled both
// sides), double-buffered, one barrier per k-step. 64KB LDS -> 2 blocks/CU.
// Operand-swapped MFMA -> C^T frags -> coalesced 8B stores.
template <bool RELU>
__global__ __launch_bounds__(256) void k_mm(const f16* __restrict__ A, const f16* __restrict__ BT,
                                            const float* __restrict__ bias, f16* __restrict__ Ch,
                                            int M, int N, int K, int nB, int nwg) {
    __shared__ f16 lsA[2][128 * 64];
    __shared__ f16 lsB[2][128 * 64];
    int wg = blockIdx.x;
    int q = nwg >> 3, r = nwg & 7;
    int xcd = wg & 7, lin = wg >> 3;
    int wgs = (xcd < r) ? (xcd * (q + 1) + lin) : (r * (q + 1) + (xcd - r) * q + lin);
    int bm = wgs / nB, bn = wgs % nB;

    int tid = threadIdx.x;
    int lane = tid & 63, wid = tid >> 6;
    int l16 = lane & 15, lhi = lane >> 4;
    int wm = (wid >> 1) * 64, wn = (wid & 1) * 64;
    int brow = bm * 128, bcol = bn * 128;

    v4f acc[4][4] = {};

    auto stageA = [&](int buf, int k0) {
#pragma unroll
        for (int it = 0; it < 4; ++it) {
            int b = it * 4096 + tid * 16;
            int row = b >> 7;
            int s = ((b >> 4) & 7) ^ (row & 7);
            gload_lds16(A + (size_t)(brow + row) * K + k0 + s * 8, ((char*)&lsA[buf][0]) + b);
        }
    };
    auto stageB = [&](int buf, int k0) {
#pragma unroll
        for (int it = 0; it < 4; ++it) {
            int b = it * 4096 + tid * 16;
            int row = b >> 7;
            int s = ((b >> 4) & 7) ^ (row & 7);
            gload_lds16(BT + (size_t)(bcol + row) * K + k0 + s * 8, ((char*)&lsB[buf][0]) + b);
        }
    };

    int nk = K >> 6;
    stageA(0, 0);
    stageB(0, 0);
    for (int kt = 0; kt < nk; ++kt) {
        int cur = kt & 1;
        __syncthreads();  // buf[cur] DMA drained; prior LDS reads done
        if (kt + 1 < nk) { stageA(cur ^ 1, (kt + 1) << 6); stageB(cur ^ 1, (kt + 1) << 6); }
#pragma unroll
        for (int ks = 0; ks < 2; ++ks) {
            half8 bf[4];
#pragma unroll
            for (int fn = 0; fn < 4; ++fn) {
                int row = wn + fn * 16 + l16;
                int sidx = (ks * 4 + lhi) ^ (row & 7);
                bf[fn] = *(const half8*)(&lsB[cur][0] + row * 64 + sidx * 8);
            }
#pragma unroll
            for (int fm = 0; fm < 4; ++fm) {
                int row = wm + fm * 16 + l16;
                int sidx = (ks * 4 + lhi) ^ (row & 7);
                half8 af = *(const half8*)(&lsA[cur][0] + row * 64 + sidx * 8);
#pragma unroll
                for (int fn = 0; fn < 4; ++fn)
                    acc[fm][fn] = __builtin_amdgcn_mfma_f32_16x16x32_f16(bf[fn], af, acc[fm][fn], 0, 0, 0);
            }
        }
    }
#pragma unroll
    for (int fm = 0; fm < 4; ++fm) {
        int m = brow + wm + fm * 16 + l16;
        if (m >= M) continue;
#pragma unroll
        for (int fn = 0; fn < 4; ++fn) {
            int nb = bcol + wn + fn * 16 + lhi * 4;
            v4f bv = *(const v4f*)(bias + nb);
            v4f v = acc[fm][fn] + bv;
            if (RELU) {
#pragma unroll
                for (int rr = 0; rr < 4; ++rr) v[rr] = fmaxf(v[rr], 0.f);
            }
            half4 hv = {(f16)v[0], (f16)v[1], (f16)v[2], (f16)v[3]};
            *(half4*)(Ch + (size_t)m * N + nb) = hv;
        }
    }
}

// ----------------------- fc2 GEMM + log_softmax ---------------------------
__global__ __launch_bounds__(256) void k_mmfc2(const f16* __restrict__ A, const f16* __restrict__ BT,
                                               const float* __restrict__ bias, float* __restrict__ out,
                                               int M, int K) {
    __shared__ f16 lsA[2][256 * 64];
    __shared__ f16 lsB[2][64 * 64];
    int bm = blockIdx.x;
    int tid = threadIdx.x;
    int lane = tid & 63, wid = tid >> 6;
    int l16 = lane & 15, lhi = lane >> 4;
    int wm = wid * 64;
    int brow = bm * 256;

    v4f acc[4][4] = {};

    auto stageA = [&](int buf, int k0) {
#pragma unroll
        for (int it = 0; it < 8; ++it) {
            int b = it * 4096 + tid * 16;
            int row = b >> 7;
            int s = ((b >> 4) & 7) ^ (row & 7);
            gload_lds16(A + (size_t)(brow + row) * K + k0 + s * 8, ((char*)&lsA[buf][0]) + b);
        }
    };
    auto stageB = [&](int buf, int k0) {
#pragma unroll
        for (int it = 0; it < 2; ++it) {
            int b = it * 4096 + tid * 16;
            int row = b >> 7;
            int s = ((b >> 4) & 7) ^ (row & 7);
            gload_lds16(BT + (size_t)row * K + k0 + s * 8, ((char*)&lsB[buf][0]) + b);
        }
    };

    int nk = K >> 6;
    stageA(0, 0);
    stageB(0, 0);
    for (int kt = 0; kt < nk; ++kt) {
        int cur = kt & 1;
        __syncthreads();
        if (kt + 1 < nk) { stageA(cur ^ 1, (kt + 1) << 6); stageB(cur ^ 1, (kt + 1) << 6); }
#pragma unroll
        for (int ks = 0; ks < 2; ++ks) {
            half8 bf[4];
#pragma unroll
            for (int fn = 0; fn < 4; ++fn) {
                int row = fn * 16 + l16;
                int sidx = (ks * 4 + lhi) ^ (row & 7);
                bf[fn] = *(const half8*)(&lsB[cur][0] + row * 64 + sidx * 8);
            }
#pragma unroll
            for (int fm = 0; fm < 4; ++fm) {
                int row = wm + fm * 16 + l16;
                int sidx = (ks * 4 + lhi) ^ (row & 7);
                half8 af = *(const half8*)(&lsA[cur][0] + row * 64 + sidx * 8);
#pragma unroll
                for (int fn = 0; fn < 4; ++fn)
                    acc[fm][fn] = __builtin_amdgcn_mfma_f32_16x16x32_f16(bf[fn], af, acc[fm][fn], 0, 0, 0);
            }
        }
    }

    float bv[4][4];
#pragma unroll
    for (int fn = 0; fn < 4; ++fn)
#pragma unroll
        for (int rr = 0; rr < 4; ++rr) {
            int nn = fn * 16 + lhi * 4 + rr;
            bv[fn][rr] = (nn < 40) ? bias[nn] : 0.f;
        }

#pragma unroll
    for (int fm = 0; fm < 4; ++fm) {
        int m = brow + wm + fm * 16 + l16;
        float v[4][4];
        float mx = -INFINITY;
#pragma unroll
        for (int fn = 0; fn < 4; ++fn)
#pragma unroll
            for (int rr = 0; rr < 4; ++rr) {
                int nn = fn * 16 + lhi * 4 + rr;
                v[fn][rr] = acc[fm][fn][rr] + bv[fn][rr];
                if (nn < 40) mx = fmaxf(mx, v[fn][rr]);
            }
        mx = fmaxf(mx, __shfl_xor(mx, 16));
        mx = fmaxf(mx, __shfl_xor(mx, 32));
        float s = 0.f;
#pragma unroll
        for (int fn = 0; fn < 3; ++fn)
#pragma unroll
            for (int rr = 0; rr < 4; ++rr) {
                int nn = fn * 16 + lhi * 4 + rr;
                if (nn < 40) s += __expf(v[fn][rr] - mx);
            }
        s += __shfl_xor(s, 16);
        s += __shfl_xor(s, 32);
        float ls = __logf(s);
        if (m < M) {
#pragma unroll
            for (int fn = 0; fn < 3; ++fn)
#pragma unroll
                for (int rr = 0; rr < 4; ++rr) {
                    int nn = fn * 16 + lhi * 4 + rr;
                    if (nn < 40) out[(size_t)m * 40 + nn] = v[fn][rr] - mx - ls;
                }
        }
    }
}

// ------------------------------ host --------------------------------------

extern "C" void kernel_launch(void* const* d_in, const int* in_sizes, int n_in,
                              void* d_out, int out_size, void* d_ws, size_t ws_size,
                              hipStream_t stream) {
    const float* x   = (const float*)d_in[0];
    const int*   ei  = (const int*)d_in[1];
    const float* ea  = (const float*)d_in[2];
    const float* W1  = (const float*)d_in[3];  const float* b1  = (const float*)d_in[4];
    const float* W2  = (const float*)d_in[5];  const float* b2  = (const float*)d_in[6];
    const float* W3  = (const float*)d_in[7];  const float* b3  = (const float*)d_in[8];
    const float* fW1 = (const float*)d_in[9];  const float* fb1 = (const float*)d_in[10];
    const float* fW2 = (const float*)d_in[11]; const float* fb2 = (const float*)d_in[12];

    int n = in_sizes[0] / 64;
    int E = in_sizes[1] / 2;
    int Mpad = ((n + 255) / 256) * 256;
    const int* src = ei;
    const int* dst = ei + E;
    float* out = (float*)d_out;

    char* p = (char*)d_ws;
    auto alloc = [&](size_t bytes) -> char* {
        char* r = p;
        p += (bytes + 255) & ~(size_t)255;
        return r;
    };
    int nb256 = (n + 255) / 256;
    u64*   packed4  = (u64*)alloc((size_t)n * 4 * 8);
    float* dinv     = (float*)alloc((size_t)n * 4);
    int*   cnt      = (int*)alloc((size_t)n * 4);
    int4*  rbase    = (int4*)alloc((size_t)n * 16);
    int*   rowptr   = (int*)alloc((size_t)(n + 1) * 4);
    int*   bsum     = (int*)alloc((size_t)nb256 * 4);
    int*   eslot    = (int*)alloc((size_t)E * 4);
    int*   csr_src  = (int*)alloc((size_t)E * 4);
    f16*   csr_norm = (f16*)alloc((size_t)E * 2);
    f16* XH  = (f16*)alloc((size_t)Mpad * 64 * 2);
    f16* W1T = (f16*)alloc((size_t)128 * 64 * 2);
    f16* W2T = (f16*)alloc((size_t)256 * 128 * 2);
    f16* W3T = (f16*)alloc((size_t)512 * 256 * 2);
    f16* F1T = (f16*)alloc((size_t)512 * 512 * 2);
    f16* F2T = (f16*)alloc((size_t)64 * 512 * 2);
    f16* AGG = (f16*)alloc((size_t)Mpad * 256 * 2);
    f16* HA  = (f16*)alloc((size_t)Mpad * 512 * 2);
    f16* HB  = (f16*)alloc((size_t)Mpad * 512 * 2);

    const int tb = 256;
    int eB = (E + tb - 1) / tb;
    int e4B = (E / 4 + tb - 1) / tb + 1;
    auto aggB = [&](int npw) {
        long waves = (n + npw - 1) / npw;
        return (int)((waves * 64 + tb - 1) / tb);
    };

    // fused prep: packed4 init + x-cast + coalesced weight transposes
    {
        PrepArgs a;
        a.packed4 = packed4; a.n4 = n * 4;
        a.x = x; a.xh = XH; a.xt4 = n * 16;
        a.W[0] = W1;  a.WT[0] = W1T; a.lgK[0] = 6; a.lgNp[0] = 7; a.N[0] = 128;
        a.W[1] = W2;  a.WT[1] = W2T; a.lgK[1] = 7; a.lgNp[1] = 8; a.N[1] = 256;
        a.W[2] = W3;  a.WT[2] = W3T; a.lgK[2] = 8; a.lgNp[2] = 9; a.N[2] = 512;
        a.W[3] = fW1; a.WT[3] = F1T; a.lgK[3] = 9; a.lgNp[3] = 9; a.N[3] = 512;
        a.W[4] = fW2; a.WT[4] = F2T; a.lgK[4] = 9; a.lgNp[4] = 6; a.N[4] = 40;
        a.off[0] = 0;
        a.off[1] = a.off[0] + 128 * 64;
        a.off[2] = a.off[1] + 256 * 128;
        a.off[3] = a.off[2] + 512 * 256;
        a.off[4] = a.off[3] + 512 * 512;
        a.off[5] = a.off[4] + 64 * 512;
        int tot = a.n4 + a.xt4 + a.off[5];
        k_prep<<<(tot + tb - 1) / tb, tb, 0, stream>>>(a);
    }

    // graph prep
    k_edge1<<<e4B, tb, 0, stream>>>(dst, ea, packed4, eslot, E, n);
    k_dinv_scan1<<<nb256, tb, 0, stream>>>(packed4, dinv, cnt, rbase, bsum, n);
    k_scan23<<<nb256, tb, 0, stream>>>(cnt, bsum, rowptr, n, E);
    k_fill<<<eB, tb, 0, stream>>>(src, dst, ea, eslot, dinv, rowptr, rbase, csr_src, csr_norm, E);

    // 128x128-tile GEMM for all conv/fc layers
    auto mm = [&](const f16* a, const f16* bt, const float* bias, f16* ch, int N, int K) {
        int nB2 = N / 128;
        int nwg = (Mpad / 128) * nB2;
        k_mm<true><<<nwg, 256, 0, stream>>>(a, bt, bias, ch, n, N, K, nB2, nwg);
    };

    // conv1: agg(xh)[.,64] -> @W1 relu -> HA[.,128]
    k_agg<64><<<aggB(8), tb, 0, stream>>>(XH, dinv, rowptr, csr_src, csr_norm, AGG, n);
    mm(AGG, W1T, b1, HA, 128, 64);
    // conv2: agg(HA)[.,128] -> @W2 relu -> HB[.,256]
    k_agg<128><<<aggB(4), tb, 0, stream>>>(HA, dinv, rowptr, csr_src, csr_norm, AGG, n);
    mm(AGG, W2T, b2, HB, 256, 128);
    // conv3: agg(HB)[.,256] -> @W3 relu -> HA[.,512]
    k_agg<256><<<aggB(2), tb, 0, stream>>>(HB, dinv, rowptr, csr_src, csr_norm, AGG, n);
    mm(AGG, W3T, b3, HA, 512, 256);
    // fc1: HA @ fW1 relu -> HB[.,512]
    mm(HA, F1T, fb1, HB, 512, 512);
    // fc2 + log_softmax fused -> out
    k_mmfc2<<<Mpad / 256, 256, 0, stream>>>(HB, F2T, fb2, out, n, 512);
}